// Round 3
// baseline (1002.421 us; speedup 1.0000x reference)
//
#include <hip/hip_runtime.h>

typedef _Float16 f16;
typedef __attribute__((ext_vector_type(8))) _Float16 f16x8;
typedef __attribute__((ext_vector_type(4))) float f32x4;

#define LOG2E 1.4426950408889634f
#define MFMA16(a, b, c) __builtin_amdgcn_mfma_f32_16x16x32_f16((a), (b), (c), 0, 0, 0)

// B=2, N=2048, C=1536, H=8, D=192.  BH=16, tokens=4096.
// d_out layout: out[2,2048,1536] f32 | attn[2,8,2048,2048] f32 | M[192,192] f32

// ---------------- fp32 -> fp16 converts ----------------
__global__ void k_cvt(const float* __restrict__ src, f16* __restrict__ dst, int n4) {
    int i = blockIdx.x * blockDim.x + threadIdx.x;
    if (i >= n4) return;
    float4 v = ((const float4*)src)[i];
    union { f16 h[4]; short4 s4; } u;
    u.h[0] = (f16)v.x; u.h[1] = (f16)v.y; u.h[2] = (f16)v.z; u.h[3] = (f16)v.w;
    ((short4*)dst)[i] = u.s4;
}

// Mt[d][e] = M[e][d]
__global__ void k_cvtM(const float* __restrict__ M, f16* __restrict__ Mt) {
    int i = blockIdx.x * 256 + threadIdx.x;
    if (i >= 192 * 192) return;
    int d = i / 192, e = i - (i / 192) * 192;
    Mt[d * 192 + e] = (f16)M[e * 192 + d];
}

// ---------------- QKV projection GEMM ----------------
__global__ __launch_bounds__(256) void k_gemm_qkv(
    const f16* __restrict__ A, const f16* __restrict__ Bw,
    f16* __restrict__ Qh, f16* __restrict__ Kh, f16* __restrict__ Vp)
{
    __shared__ __align__(16) f16 As[128 * 32];
    __shared__ __align__(16) f16 Bs[128 * 32];
    const int tid = threadIdx.x;
    const int lane = tid & 63, w = tid >> 6;
    const int m0 = blockIdx.y * 128, n0 = blockIdx.x * 128;
    const int wm = (w & 1) * 64, wn = (w >> 1) * 64;
    const int L = lane & 15, g = lane >> 4;
    const char* Ab = (const char*)A;
    const char* Bb = (const char*)Bw;
    char* AsB = (char*)As; char* BsB = (char*)Bs;

    f32x4 acc[4][4] = {};
    int4 ra[2], rb[2];
    const int s0 = tid, s1 = tid + 256;
#define LD_A(kk, s) (*(const int4*)(Ab + (size_t)(m0 + ((s) >> 2)) * 3072 + (kk) * 64 + ((s) & 3) * 16))
#define LD_B(kk, s) (*(const int4*)(Bb + (size_t)(n0 + ((s) >> 2)) * 3072 + (kk) * 64 + ((s) & 3) * 16))
    ra[0] = LD_A(0, s0); ra[1] = LD_A(0, s1);
    rb[0] = LD_B(0, s0); rb[1] = LD_B(0, s1);
    for (int kk = 0; kk < 48; ++kk) {
        __syncthreads();
        *(int4*)(AsB + s0 * 16) = ra[0]; *(int4*)(AsB + s1 * 16) = ra[1];
        *(int4*)(BsB + s0 * 16) = rb[0]; *(int4*)(BsB + s1 * 16) = rb[1];
        __syncthreads();
        if (kk + 1 < 48) {
            ra[0] = LD_A(kk + 1, s0); ra[1] = LD_A(kk + 1, s1);
            rb[0] = LD_B(kk + 1, s0); rb[1] = LD_B(kk + 1, s1);
        }
        f16x8 af[4], bf[4];
#pragma unroll
        for (int i = 0; i < 4; ++i) {
            af[i] = *(const f16x8*)(AsB + (wm + i * 16 + L) * 64 + g * 16);
            bf[i] = *(const f16x8*)(BsB + (wn + i * 16 + L) * 64 + g * 16);
        }
#pragma unroll
        for (int i = 0; i < 4; ++i)
#pragma unroll
            for (int j = 0; j < 4; ++j)
                acc[i][j] = MFMA16(af[i], bf[j], acc[i][j]);
    }
#pragma unroll
    for (int i = 0; i < 4; ++i)
#pragma unroll
        for (int j = 0; j < 4; ++j) {
            int gn = n0 + wn + j * 16 + L;
            int sec = gn / 1536;
            int rem = gn - sec * 1536;
            int h = rem / 192;
            int d = rem - h * 192;
            int gm = m0 + wm + i * 16 + g * 4;
            int gb = gm >> 11, nn = gm & 2047;
            if (sec == 2) {
                union { f16 h4[4]; short4 s4; } u;
#pragma unroll
                for (int r = 0; r < 4; ++r) u.h4[r] = (f16)acc[i][j][r];
                int nnp = (nn & ~31) | (((nn >> 2) & 3) << 3) | (((nn >> 4) & 1) << 2);
                *(short4*)(Vp + (size_t)((gb * 8 + h) * 192 + d) * 2048 + nnp) = u.s4;
            } else {
                f16* dst = (sec == 0 ? Qh : Kh) + (size_t)((gb * 8 + h) * 2048 + nn) * 192 + d;
#pragma unroll
                for (int r = 0; r < 4; ++r) dst[(size_t)r * 192] = (f16)acc[i][j][r];
            }
        }
#undef LD_A
#undef LD_B
}

// ---------------- apply metric M (+ fused kMk for the K branch) ----------------
__global__ __launch_bounds__(256) void k_mgemm(
    const f16* __restrict__ Qh, const f16* __restrict__ Kh,
    const f16* __restrict__ Mt, f16* __restrict__ QMh, f16* __restrict__ KMh,
    const float* __restrict__ scale_p, float* __restrict__ kmk)
{
    const int tid = threadIdx.x, lane = tid & 63, w = tid >> 6;
    const int L = lane & 15, g = lane >> 4;
    const int isK = blockIdx.y;
    const f16* src = isK ? Kh : Qh;
    f16* dst = isK ? KMh : QMh;
    const int row0 = blockIdx.x * 64 + w * 16;
    f16x8 af[6];
#pragma unroll
    for (int ks = 0; ks < 6; ++ks)
        af[ks] = *(const f16x8*)((const char*)src + (size_t)(row0 + L) * 384 + ks * 64 + g * 16);
    f32x4 acc[12] = {};
#pragma unroll
    for (int ct = 0; ct < 12; ++ct)
#pragma unroll
        for (int ks = 0; ks < 6; ++ks) {
            f16x8 bf = *(const f16x8*)((const char*)Mt + (ct * 16 + L) * 384 + ks * 64 + g * 16);
            acc[ct] = MFMA16(af[ks], bf, acc[ct]);
        }
#pragma unroll
    for (int ct = 0; ct < 12; ++ct)
#pragma unroll
        for (int r = 0; r < 4; ++r)
            dst[(size_t)(row0 + g * 4 + r) * 192 + ct * 16 + L] = (f16)acc[ct][r];
    if (isK) {
        // kMk[row] = sum_d K[row][d]*KM[row][d]; lane holds KM[row][ct*16+L] in acc
        float s[4] = {0.f, 0.f, 0.f, 0.f};
#pragma unroll
        for (int r = 0; r < 4; ++r) {
            int row = row0 + g * 4 + r;
#pragma unroll
            for (int ct = 0; ct < 12; ++ct)
                s[r] += acc[ct][r] * (float)Kh[(size_t)row * 192 + ct * 16 + L];
        }
#pragma unroll
        for (int r = 0; r < 4; ++r) {
            s[r] += __shfl_xor(s[r], 1); s[r] += __shfl_xor(s[r], 2);
            s[r] += __shfl_xor(s[r], 4); s[r] += __shfl_xor(s[r], 8);
        }
        if (L == 0) {
            float sc = scale_p[0] * LOG2E;
#pragma unroll
            for (int r = 0; r < 4; ++r) kmk[row0 + g * 4 + r] = s[r] * sc;
        }
    }
}

// ---------------- fused two-pass flash attention, barrier-free main loops ----------------
// grid 1024: bh = (bx&7)*2 + (bx>>9) (XCD-grouped), rb = (bx>>3)&63 -> rows [rb*32, rb*32+32)
// 4 waves: wr = w&1 picks 16-row group, half = w>>1 picks column half [half*1024, +1024).
// K/V read DIRECTLY from L2 (no LDS, no barriers in the chunk loops).
__global__ __launch_bounds__(256) void k_attn(
    const f16* __restrict__ QMh, const f16* __restrict__ Kh,
    const f16* __restrict__ Vp, const float* __restrict__ kmk,
    const float* __restrict__ scale_p,
    float* __restrict__ attn, f16* __restrict__ ctx)
{
    __shared__ float mlbuf[2][4][16];
    __shared__ __align__(16) float cbuf[2][64][48];   // 24 KB PV-combine buffer
    const int tid = threadIdx.x, lane = tid & 63, w = tid >> 6;
    const int L = lane & 15, g = lane >> 4;
    const int bx = blockIdx.x;
    const int bh = (bx & 7) * 2 + (bx >> 9);
    const int rb = (bx >> 3) & 63;
    const int wr = w & 1, half = w >> 1;
    const int row0 = rb * 32 + wr * 16;
    const float a2 = 2.f * scale_p[0] * LOG2E;

    const char* qbase = (const char*)QMh + (size_t)(bh * 2048 + row0) * 384;
    f16x8 qf[6];
#pragma unroll
    for (int ks = 0; ks < 6; ++ks)
        qf[ks] = *(const f16x8*)(qbase + L * 384 + ks * 64 + g * 16);
    const char* Kb = (const char*)Kh + (size_t)bh * 2048 * 384;
    const char* Vb = (const char*)Vp + (size_t)bh * 192 * 4096;
    const float* kmkrow = kmk + bh * 2048;
    const int c0 = half * 32, c1 = c0 + 32;

    // ---------------- pass A: online max + sum over this wave's column half ----------------
    float m_run = -3.0e38f, l_run = 0.f;
    for (int c = c0; c < c1; ++c) {
        f32x4 a0 = {}, a1 = {};
#pragma unroll
        for (int ks = 0; ks < 6; ++ks) {
            f16x8 kf0 = *(const f16x8*)(Kb + (size_t)(c * 32 + L) * 384 + ks * 64 + g * 16);
            f16x8 kf1 = *(const f16x8*)(Kb + (size_t)(c * 32 + 16 + L) * 384 + ks * 64 + g * 16);
            a0 = MFMA16(kf0, qf[ks], a0);
            a1 = MFMA16(kf1, qf[ks], a1);
        }
        float4 km0 = *(const float4*)(kmkrow + c * 32 + g * 4);
        float4 km1 = *(const float4*)(kmkrow + c * 32 + 16 + g * 4);
        float s8[8];
        s8[0] = a2 * a0[0] - km0.x; s8[1] = a2 * a0[1] - km0.y;
        s8[2] = a2 * a0[2] - km0.z; s8[3] = a2 * a0[3] - km0.w;
        s8[4] = a2 * a1[0] - km1.x; s8[5] = a2 * a1[1] - km1.y;
        s8[6] = a2 * a1[2] - km1.z; s8[7] = a2 * a1[3] - km1.w;
        float mx = fmaxf(fmaxf(fmaxf(s8[0], s8[1]), fmaxf(s8[2], s8[3])),
                         fmaxf(fmaxf(s8[4], s8[5]), fmaxf(s8[6], s8[7])));
        mx = fmaxf(mx, __shfl_xor(mx, 16));
        mx = fmaxf(mx, __shfl_xor(mx, 32));
        float mn = fmaxf(m_run, mx);
        float sum = 0.f;
#pragma unroll
        for (int j = 0; j < 8; ++j) sum += __builtin_amdgcn_exp2f(s8[j] - mn);
        sum += __shfl_xor(sum, 16);
        sum += __shfl_xor(sum, 32);
        l_run = l_run * __builtin_amdgcn_exp2f(m_run - mn) + sum;
        m_run = mn;
    }
    // combine (m,l) across the two column halves
    if (lane < 16) { mlbuf[0][w][L] = m_run; mlbuf[1][w][L] = l_run; }
    __syncthreads();
    float moff;
    {
        int pw = w ^ 2;
        float m2 = mlbuf[0][pw][L], l2 = mlbuf[1][pw][L];
        float mt = fmaxf(m_run, m2);
        float lt = l_run * __builtin_amdgcn_exp2f(m_run - mt)
                 + l2   * __builtin_amdgcn_exp2f(m2 - mt);
        moff = mt + __log2f(lt);   // p = exp2(s - moff) is final normalized
    }

    // ---------------- pass B: recompute + write normalized attn + PV ----------------
    f32x4 cacc[12] = {};
    float* arow = attn + (size_t)(bh * 2048 + row0 + L) * 2048;
    for (int c = c0; c < c1; ++c) {
        f32x4 a0 = {}, a1 = {};
#pragma unroll
        for (int ks = 0; ks < 6; ++ks) {
            f16x8 kf0 = *(const f16x8*)(Kb + (size_t)(c * 32 + L) * 384 + ks * 64 + g * 16);
            f16x8 kf1 = *(const f16x8*)(Kb + (size_t)(c * 32 + 16 + L) * 384 + ks * 64 + g * 16);
            a0 = MFMA16(kf0, qf[ks], a0);
            a1 = MFMA16(kf1, qf[ks], a1);
        }
        float4 km0 = *(const float4*)(kmkrow + c * 32 + g * 4);
        float4 km1 = *(const float4*)(kmkrow + c * 32 + 16 + g * 4);
        float p[8];
        p[0] = __builtin_amdgcn_exp2f(a2 * a0[0] - km0.x - moff);
        p[1] = __builtin_amdgcn_exp2f(a2 * a0[1] - km0.y - moff);
        p[2] = __builtin_amdgcn_exp2f(a2 * a0[2] - km0.z - moff);
        p[3] = __builtin_amdgcn_exp2f(a2 * a0[3] - km0.w - moff);
        p[4] = __builtin_amdgcn_exp2f(a2 * a1[0] - km1.x - moff);
        p[5] = __builtin_amdgcn_exp2f(a2 * a1[1] - km1.y - moff);
        p[6] = __builtin_amdgcn_exp2f(a2 * a1[2] - km1.z - moff);
        p[7] = __builtin_amdgcn_exp2f(a2 * a1[3] - km1.w - moff);
        *(float4*)(arow + c * 32 + g * 4)      = make_float4(p[0], p[1], p[2], p[3]);
        *(float4*)(arow + c * 32 + 16 + g * 4) = make_float4(p[4], p[5], p[6], p[7]);
        f16x8 pa;
        pa[0] = (f16)p[0]; pa[1] = (f16)p[1]; pa[2] = (f16)p[2]; pa[3] = (f16)p[3];
        pa[4] = (f16)p[4]; pa[5] = (f16)p[5]; pa[6] = (f16)p[6]; pa[7] = (f16)p[7];
#pragma unroll
        for (int dt = 0; dt < 12; ++dt) {
            f16x8 vf = *(const f16x8*)(Vb + (size_t)(dt * 16 + L) * 4096 + c * 64 + g * 16);
            cacc[dt] = MFMA16(pa, vf, cacc[dt]);
        }
    }

    // ---------------- combine PV partial sums across column halves ----------------
    if (w >= 2) {
#pragma unroll
        for (int dt = 0; dt < 12; ++dt)
            *(f32x4*)&cbuf[w - 2][lane][dt * 4] = cacc[dt];
    }
    __syncthreads();
    if (w < 2) {
        const int b = bh >> 3, h = bh & 7;
#pragma unroll
        for (int dt = 0; dt < 12; ++dt) {
            f32x4 o = *(const f32x4*)&cbuf[w][lane][dt * 4];
            cacc[dt][0] += o[0]; cacc[dt][1] += o[1];
            cacc[dt][2] += o[2]; cacc[dt][3] += o[3];
#pragma unroll
            for (int r = 0; r < 4; ++r)
                ctx[(size_t)(b * 2048 + row0 + g * 4 + r) * 1536 + h * 192 + dt * 16 + L] = (f16)cacc[dt][r];
        }
    }
}

// ---------------- output projection GEMM + bias ----------------
__global__ __launch_bounds__(256) void k_proj(
    const f16* __restrict__ A, const f16* __restrict__ Bw,
    const float* __restrict__ bias, float* __restrict__ out)
{
    __shared__ __align__(16) f16 As[128 * 32];
    __shared__ __align__(16) f16 Bs[128 * 32];
    const int tid = threadIdx.x;
    const int lane = tid & 63, w = tid >> 6;
    const int m0 = blockIdx.y * 128, n0 = blockIdx.x * 128;
    const int wm = (w & 1) * 64, wn = (w >> 1) * 64;
    const int L = lane & 15, g = lane >> 4;
    const char* Ab = (const char*)A;
    const char* Bb = (const char*)Bw;
    char* AsB = (char*)As; char* BsB = (char*)Bs;

    f32x4 acc[4][4] = {};
    int4 ra[2], rb[2];
    const int s0 = tid, s1 = tid + 256;
#define LD_A(kk, s) (*(const int4*)(Ab + (size_t)(m0 + ((s) >> 2)) * 3072 + (kk) * 64 + ((s) & 3) * 16))
#define LD_B(kk, s) (*(const int4*)(Bb + (size_t)(n0 + ((s) >> 2)) * 3072 + (kk) * 64 + ((s) & 3) * 16))
    ra[0] = LD_A(0, s0); ra[1] = LD_A(0, s1);
    rb[0] = LD_B(0, s0); rb[1] = LD_B(0, s1);
    for (int kk = 0; kk < 48; ++kk) {
        __syncthreads();
        *(int4*)(AsB + s0 * 16) = ra[0]; *(int4*)(AsB + s1 * 16) = ra[1];
        *(int4*)(BsB + s0 * 16) = rb[0]; *(int4*)(BsB + s1 * 16) = rb[1];
        __syncthreads();
        if (kk + 1 < 48) {
            ra[0] = LD_A(kk + 1, s0); ra[1] = LD_A(kk + 1, s1);
            rb[0] = LD_B(kk + 1, s0); rb[1] = LD_B(kk + 1, s1);
        }
        f16x8 af[4], bf[4];
#pragma unroll
        for (int i = 0; i < 4; ++i) {
            af[i] = *(const f16x8*)(AsB + (wm + i * 16 + L) * 64 + g * 16);
            bf[i] = *(const f16x8*)(BsB + (wn + i * 16 + L) * 64 + g * 16);
        }
#pragma unroll
        for (int i = 0; i < 4; ++i)
#pragma unroll
            for (int j = 0; j < 4; ++j)
                acc[i][j] = MFMA16(af[i], bf[j], acc[i][j]);
    }
#pragma unroll
    for (int i = 0; i < 4; ++i)
#pragma unroll
        for (int j = 0; j < 4; ++j) {
            int gn = n0 + wn + j * 16 + L;
            float bv = bias[gn];
            int gm = m0 + wm + i * 16 + g * 4;
            float* dst = out + (size_t)gm * 1536 + gn;
#pragma unroll
            for (int r = 0; r < 4; ++r) dst[(size_t)r * 1536] = acc[i][j][r] + bv;
        }
#undef LD_A
#undef LD_B
}

extern "C" void kernel_launch(void* const* d_in, const int* in_sizes, int n_in,
                              void* d_out, int out_size, void* d_ws, size_t ws_size,
                              hipStream_t stream)
{
    const float* x     = (const float*)d_in[0];
    const float* Wqkv  = (const float*)d_in[1];
    const float* Wproj = (const float*)d_in[2];
    const float* bproj = (const float*)d_in[3];
    const float* scale = (const float*)d_in[4];
    const float* M     = (const float*)d_in[5];
    float* out  = (float*)d_out;
    float* attn = out + 6291456;

    char* p = (char*)d_ws;
    f16* x_h     = (f16*)p;  p += 12582912;
    f16* Wqkv_h  = (f16*)p;  p += 14155776;
    f16* Wproj_h = (f16*)p;  p += 4718592;
    f16* Mt_h    = (f16*)p;  p += 73728;
    f16* Qh      = (f16*)p;  p += 12582912;
    f16* Kh      = (f16*)p;  p += 12582912;
    f16* Vp      = (f16*)p;  p += 12582912;
    f16* QMh     = (f16*)p;  p += 12582912;
    f16* KMh     = (f16*)p;  p += 12582912;
    float* kmk   = (float*)p; p += 131072;
    f16* ctx     = (f16*)p;  p += 12582912;

    k_cvt<<<6144, 256, 0, stream>>>(x, x_h, 1572864);
    k_cvt<<<6912, 256, 0, stream>>>(Wqkv, Wqkv_h, 1769472);
    k_cvt<<<2304, 256, 0, stream>>>(Wproj, Wproj_h, 589824);
    k_cvtM<<<144, 256, 0, stream>>>(M, Mt_h);
    k_gemm_qkv<<<dim3(36, 32), 256, 0, stream>>>(x_h, Wqkv_h, Qh, Kh, Vp);
    k_mgemm<<<dim3(512, 2), 256, 0, stream>>>(Qh, Kh, Mt_h, QMh, KMh, scale, kmk);
    k_attn<<<1024, 256, 0, stream>>>(QMh, Kh, Vp, kmk, scale, attn, ctx);
    k_proj<<<dim3(12, 32), 256, 0, stream>>>(ctx, Wproj_h, bproj, out);
    hipMemcpyAsync(out + 73400320, M, 36864 * 4, hipMemcpyDeviceToDevice, stream);
}

// Round 6
// 686.834 us; speedup vs baseline: 1.4595x; 1.4595x over previous
//
#include <hip/hip_runtime.h>

typedef _Float16 f16;
typedef __attribute__((ext_vector_type(8))) _Float16 f16x8;
typedef __attribute__((ext_vector_type(4))) float f32x4;

#define LOG2E 1.4426950408889634f
#define MFMA16(a, b, c) __builtin_amdgcn_mfma_f32_16x16x32_f16((a), (b), (c), 0, 0, 0)

// B=2, N=2048, C=1536, H=8, D=192.  BH=16, tokens=4096.
// d_out layout: out[2,2048,1536] f32 | attn[2,8,2048,2048] f32 | M[192,192] f32

// ---------------- fp32 -> fp16 converts ----------------
__global__ void k_cvt(const float* __restrict__ src, f16* __restrict__ dst, int n4) {
    int i = blockIdx.x * blockDim.x + threadIdx.x;
    if (i >= n4) return;
    float4 v = ((const float4*)src)[i];
    union { f16 h[4]; short4 s4; } u;
    u.h[0] = (f16)v.x; u.h[1] = (f16)v.y; u.h[2] = (f16)v.z; u.h[3] = (f16)v.w;
    ((short4*)dst)[i] = u.s4;
}

// Mt[d][e] = M[e][d]
__global__ void k_cvtM(const float* __restrict__ M, f16* __restrict__ Mt) {
    int i = blockIdx.x * 256 + threadIdx.x;
    if (i >= 192 * 192) return;
    int d = i / 192, e = i - (i / 192) * 192;
    Mt[d * 192 + e] = (f16)M[e * 192 + d];
}

// ---------------- QKV projection GEMM (80B-padded LDS rows) ----------------
__global__ __launch_bounds__(256) void k_gemm_qkv(
    const f16* __restrict__ A, const f16* __restrict__ Bw,
    f16* __restrict__ Qh, f16* __restrict__ Kh, f16* __restrict__ Vp)
{
    __shared__ __align__(16) char AsB[128 * 80];
    __shared__ __align__(16) char BsB[128 * 80];
    const int tid = threadIdx.x;
    const int lane = tid & 63, w = tid >> 6;
    const int m0 = blockIdx.y * 128, n0 = blockIdx.x * 128;
    const int wm = (w & 1) * 64, wn = (w >> 1) * 64;
    const int L = lane & 15, g = lane >> 4;
    const char* Ab = (const char*)A;
    const char* Bb = (const char*)Bw;

    f32x4 acc[4][4] = {};
    int4 ra[2], rb[2];
    const int s0 = tid, s1 = tid + 256;
    const int d0 = (tid >> 2) * 80 + (tid & 3) * 16;
    const int d1 = d0 + 5120;
#define LD_A(kk, s) (*(const int4*)(Ab + (size_t)(m0 + ((s) >> 2)) * 3072 + (kk) * 64 + ((s) & 3) * 16))
#define LD_B(kk, s) (*(const int4*)(Bb + (size_t)(n0 + ((s) >> 2)) * 3072 + (kk) * 64 + ((s) & 3) * 16))
    ra[0] = LD_A(0, s0); ra[1] = LD_A(0, s1);
    rb[0] = LD_B(0, s0); rb[1] = LD_B(0, s1);
    for (int kk = 0; kk < 48; ++kk) {
        __syncthreads();
        *(int4*)(AsB + d0) = ra[0]; *(int4*)(AsB + d1) = ra[1];
        *(int4*)(BsB + d0) = rb[0]; *(int4*)(BsB + d1) = rb[1];
        __syncthreads();
        if (kk + 1 < 48) {
            ra[0] = LD_A(kk + 1, s0); ra[1] = LD_A(kk + 1, s1);
            rb[0] = LD_B(kk + 1, s0); rb[1] = LD_B(kk + 1, s1);
        }
        f16x8 af[4], bf[4];
#pragma unroll
        for (int i = 0; i < 4; ++i) {
            af[i] = *(const f16x8*)(AsB + (wm + i * 16 + L) * 80 + g * 16);
            bf[i] = *(const f16x8*)(BsB + (wn + i * 16 + L) * 80 + g * 16);
        }
#pragma unroll
        for (int i = 0; i < 4; ++i)
#pragma unroll
            for (int j = 0; j < 4; ++j)
                acc[i][j] = MFMA16(af[i], bf[j], acc[i][j]);
    }
#pragma unroll
    for (int i = 0; i < 4; ++i)
#pragma unroll
        for (int j = 0; j < 4; ++j) {
            int gn = n0 + wn + j * 16 + L;
            int sec = gn / 1536;
            int rem = gn - sec * 1536;
            int h = rem / 192;
            int d = rem - h * 192;
            int gm = m0 + wm + i * 16 + g * 4;
            int gb = gm >> 11, nn = gm & 2047;
            if (sec == 2) {
                union { f16 h4[4]; short4 s4; } u;
#pragma unroll
                for (int r = 0; r < 4; ++r) u.h4[r] = (f16)acc[i][j][r];
                // slot s = (((t>>2)&3)<<3) | (((t>>4)&1)<<2) | (t&3) within each 32-block
                int nnp = (nn & ~31) | (((nn >> 2) & 3) << 3) | (((nn >> 4) & 1) << 2) | (nn & 3);
                *(short4*)(Vp + (size_t)((gb * 8 + h) * 192 + d) * 2048 + nnp) = u.s4;
            } else {
                f16* dst = (sec == 0 ? Qh : Kh) + (size_t)((gb * 8 + h) * 2048 + nn) * 192 + d;
#pragma unroll
                for (int r = 0; r < 4; ++r) dst[(size_t)r * 192] = (f16)acc[i][j][r];
            }
        }
#undef LD_A
#undef LD_B
}

// ---------------- apply metric M + row quadratic forms ----------------
__global__ __launch_bounds__(256) void k_mgemm(
    const f16* __restrict__ Qh, const f16* __restrict__ Kh,
    const f16* __restrict__ Mt, f16* __restrict__ QMh,
    const float* __restrict__ scale_p, float* __restrict__ qmq, float* __restrict__ kmk)
{
    const int tid = threadIdx.x, lane = tid & 63, w = tid >> 6;
    const int L = lane & 15, g = lane >> 4;
    const int isK = blockIdx.y;
    const f16* src = isK ? Kh : Qh;
    float* rowdot = isK ? kmk : qmq;
    const int row0 = blockIdx.x * 64 + w * 16;
    f16x8 af[6];
#pragma unroll
    for (int ks = 0; ks < 6; ++ks)
        af[ks] = *(const f16x8*)((const char*)src + (size_t)(row0 + L) * 384 + ks * 64 + g * 16);
    f32x4 acc[12] = {};
#pragma unroll
    for (int ct = 0; ct < 12; ++ct)
#pragma unroll
        for (int ks = 0; ks < 6; ++ks) {
            f16x8 bf = *(const f16x8*)((const char*)Mt + (ct * 16 + L) * 384 + ks * 64 + g * 16);
            acc[ct] = MFMA16(af[ks], bf, acc[ct]);
        }
    if (!isK) {
#pragma unroll
        for (int ct = 0; ct < 12; ++ct)
#pragma unroll
            for (int r = 0; r < 4; ++r)
                QMh[(size_t)(row0 + g * 4 + r) * 192 + ct * 16 + L] = (f16)acc[ct][r];
    }
    float s[4] = {0.f, 0.f, 0.f, 0.f};
#pragma unroll
    for (int r = 0; r < 4; ++r) {
        int row = row0 + g * 4 + r;
#pragma unroll
        for (int ct = 0; ct < 12; ++ct)
            s[r] += acc[ct][r] * (float)src[(size_t)row * 192 + ct * 16 + L];
    }
#pragma unroll
    for (int r = 0; r < 4; ++r) {
        s[r] += __shfl_xor(s[r], 1); s[r] += __shfl_xor(s[r], 2);
        s[r] += __shfl_xor(s[r], 4); s[r] += __shfl_xor(s[r], 8);
    }
    if (L == 0) {
        float sc = scale_p[0] * LOG2E;
#pragma unroll
        for (int r = 0; r < 4; ++r) rowdot[row0 + g * 4 + r] = s[r] * sc;
    }
}

// ---------------- single-pass attention ----------------
// attn gets absolute p = exp2(e) in fp32 (normalized later by k_norm).
// PV uses p_sh = p * 2^-m_run(row); m_run deferred-updated (wave-uniform DECISION
// via __any, PER-ROW factors remapped to accumulator rows via shfl).
__global__ __launch_bounds__(256) void k_attn(
    const f16* __restrict__ QMh, const f16* __restrict__ Kh,
    const f16* __restrict__ Vp, const float* __restrict__ kmk,
    const float* __restrict__ qmq, const float* __restrict__ scale_p,
    float* __restrict__ attn, f16* __restrict__ ctx, float* __restrict__ lrow)
{
    __shared__ __align__(16) char KsB[2][12288];   // [32 k-rows][384B], slot^(row&7) swizzle
    __shared__ __align__(16) char VsB[2][15360];   // [192 d][64B] padded to 80B rows
    const int tid = threadIdx.x, lane = tid & 63, w = tid >> 6;
    const int L = lane & 15, g = lane >> 4;
    const int bx = blockIdx.x;
    const int bh = (bx & 7) * 2 + (bx >> 8);
    const int qb = (bx >> 3) & 31;
    const int row0 = qb * 64 + w * 16;
    const float a2 = 2.f * scale_p[0] * LOG2E;

    const char* qbase = (const char*)QMh + (size_t)(bh * 2048 + row0) * 384;
    f16x8 qf[6];
#pragma unroll
    for (int ks = 0; ks < 6; ++ks)
        qf[ks] = *(const f16x8*)(qbase + L * 384 + ks * 64 + g * 16);
    const char* Kb = (const char*)Kh + (size_t)bh * 2048 * 384;
    const char* Vb = (const char*)Vp + (size_t)bh * 192 * 4096;
    const float* kmkrow = kmk + bh * 2048;
    const float Crow = qmq[bh * 2048 + row0 + L];

    int ksrc[3], kdst[3], vsrc[3], vdst[3];
#pragma unroll
    for (int i = 0; i < 3; ++i) {
        int s = tid + 256 * i;
        int r = s / 24, cc = s - r * 24;
        ksrc[i] = r * 384 + cc * 16;
        kdst[i] = r * 384 + (((cc & ~7) | ((cc & 7) ^ (r & 7))) << 4);
        vsrc[i] = (s >> 2) * 4096 + (s & 3) * 16;
        vdst[i] = (s >> 2) * 80 + (s & 3) * 16;
    }
    int kslot[6];
#pragma unroll
    for (int ks = 0; ks < 6; ++ks) {
        int slot = ks * 4 + g;
        kslot[ks] = (((slot & ~7) | ((slot & 7) ^ (L & 7))) << 4);
    }

    int4 stk[3], stv[3];
#pragma unroll
    for (int i = 0; i < 3; ++i) {
        stk[i] = *(const int4*)(Kb + ksrc[i]);
        stv[i] = *(const int4*)(Vb + vsrc[i]);
    }
    f32x4 cacc[12] = {};
    float lacc = 0.f;
    float m_run = -3.0e38f, sc = 0.f;
    float* arow = attn + (size_t)(bh * 2048 + row0 + L) * 2048;

    for (int c = 0; c < 64; ++c) {
        char* Kl = KsB[c & 1];
        char* Vl = VsB[c & 1];
#pragma unroll
        for (int i = 0; i < 3; ++i) {
            *(int4*)(Kl + kdst[i]) = stk[i];
            *(int4*)(Vl + vdst[i]) = stv[i];
        }
        if (c < 63) {
#pragma unroll
            for (int i = 0; i < 3; ++i) {
                stk[i] = *(const int4*)(Kb + (size_t)(c + 1) * 12288 + ksrc[i]);
                stv[i] = *(const int4*)(Vb + (size_t)(c + 1) * 64 + vsrc[i]);
            }
        }
        __syncthreads();
        f32x4 a0 = {}, a1 = {};
#pragma unroll
        for (int ks = 0; ks < 6; ++ks) {
            f16x8 kf0 = *(const f16x8*)(Kl + L * 384 + kslot[ks]);
            f16x8 kf1 = *(const f16x8*)(Kl + (16 + L) * 384 + kslot[ks]);
            a0 = MFMA16(kf0, qf[ks], a0);
            a1 = MFMA16(kf1, qf[ks], a1);
        }
        float4 km0 = *(const float4*)(kmkrow + c * 32 + g * 4);
        float4 km1 = *(const float4*)(kmkrow + c * 32 + 16 + g * 4);
        float e8[8];
        e8[0] = a2 * a0[0] - km0.x - Crow;
        e8[1] = a2 * a0[1] - km0.y - Crow;
        e8[2] = a2 * a0[2] - km0.z - Crow;
        e8[3] = a2 * a0[3] - km0.w - Crow;
        e8[4] = a2 * a1[0] - km1.x - Crow;
        e8[5] = a2 * a1[1] - km1.y - Crow;
        e8[6] = a2 * a1[2] - km1.z - Crow;
        e8[7] = a2 * a1[3] - km1.w - Crow;
        // per-row (L) chunk max: reduce over the 4 g-replicas of this row
        float mx = fmaxf(fmaxf(fmaxf(e8[0], e8[1]), fmaxf(e8[2], e8[3])),
                         fmaxf(fmaxf(e8[4], e8[5]), fmaxf(e8[6], e8[7])));
        mx = fmaxf(mx, __shfl_xor(mx, 16));
        mx = fmaxf(mx, __shfl_xor(mx, 32));
        // deferred rescale: wave-uniform decision, per-row factors
        if (__any(mx > m_run + 4.f)) {
            float mnew = fmaxf(m_run, mx);                       // per-row
            float fr = __builtin_amdgcn_exp2f(m_run - mnew);     // per-row (L)
            lacc *= fr;
            float frc[4];
#pragma unroll
            for (int r = 0; r < 4; ++r) frc[r] = __shfl(fr, g * 4 + r);  // acc-row remap
#pragma unroll
            for (int dt = 0; dt < 12; ++dt) {
#pragma unroll
                for (int r = 0; r < 4; ++r) cacc[dt][r] *= frc[r];
            }
            m_run = mnew;
            sc = __builtin_amdgcn_exp2f(-m_run);
        }
        float p[8], ps[8];
#pragma unroll
        for (int j = 0; j < 8; ++j) {
            p[j] = __builtin_amdgcn_exp2f(e8[j]);
            ps[j] = p[j] * sc;
        }
        *(float4*)(arow + c * 32 + g * 4)      = make_float4(p[0], p[1], p[2], p[3]);
        *(float4*)(arow + c * 32 + 16 + g * 4) = make_float4(p[4], p[5], p[6], p[7]);
        lacc += ((ps[0] + ps[1]) + (ps[2] + ps[3])) + ((ps[4] + ps[5]) + (ps[6] + ps[7]));
        f16x8 pa;
        pa[0] = (f16)ps[0]; pa[1] = (f16)ps[1]; pa[2] = (f16)ps[2]; pa[3] = (f16)ps[3];
        pa[4] = (f16)ps[4]; pa[5] = (f16)ps[5]; pa[6] = (f16)ps[6]; pa[7] = (f16)ps[7];
#pragma unroll
        for (int dt = 0; dt < 12; ++dt) {
            f16x8 vf = *(const f16x8*)(Vl + (dt * 16 + L) * 80 + g * 16);
            cacc[dt] = MFMA16(pa, vf, cacc[dt]);
        }
    }
    // reduce l over the 4 g-groups (each L-column holds one q-row)
    lacc += __shfl_xor(lacc, 16);
    lacc += __shfl_xor(lacc, 32);
    if (g == 0) lrow[bh * 2048 + row0 + L] = __builtin_amdgcn_exp2f(-m_run) / lacc;
    float linv_r[4];
#pragma unroll
    for (int r = 0; r < 4; ++r) linv_r[r] = 1.f / __shfl(lacc, g * 4 + r);
    const int b = bh >> 3, h = bh & 7;
#pragma unroll
    for (int dt = 0; dt < 12; ++dt)
#pragma unroll
        for (int r = 0; r < 4; ++r)
            ctx[(size_t)(b * 2048 + row0 + g * 4 + r) * 1536 + h * 192 + dt * 16 + L]
                = (f16)(cacc[dt][r] * linv_r[r]);
}

// ---------------- streaming in-place normalize of attn (32768 rows) ----------------
__global__ __launch_bounds__(256) void k_norm(float* __restrict__ attn,
                                              const float* __restrict__ lrow)
{
    const int row = blockIdx.x * 8 + (threadIdx.x >> 5);
    const int t = threadIdx.x & 31;
    const float f = lrow[row];    // absolute inverse row sum
    float4* p = (float4*)(attn + (size_t)row * 2048) + t;
#pragma unroll
    for (int i = 0; i < 16; ++i) {
        float4 v = p[(size_t)i * 32];
        v.x *= f; v.y *= f; v.z *= f; v.w *= f;
        p[(size_t)i * 32] = v;
    }
}

// ---------------- output projection GEMM + bias (80B-padded LDS rows) ----------------
__global__ __launch_bounds__(256) void k_proj(
    const f16* __restrict__ A, const f16* __restrict__ Bw,
    const float* __restrict__ bias, float* __restrict__ out)
{
    __shared__ __align__(16) char AsB[128 * 80];
    __shared__ __align__(16) char BsB[128 * 80];
    const int tid = threadIdx.x;
    const int lane = tid & 63, w = tid >> 6;
    const int m0 = blockIdx.y * 128, n0 = blockIdx.x * 128;
    const int wm = (w & 1) * 64, wn = (w >> 1) * 64;
    const int L = lane & 15, g = lane >> 4;
    const char* Ab = (const char*)A;
    const char* Bb = (const char*)Bw;

    f32x4 acc[4][4] = {};
    int4 ra[2], rb[2];
    const int s0 = tid, s1 = tid + 256;
    const int d0 = (tid >> 2) * 80 + (tid & 3) * 16;
    const int d1 = d0 + 5120;
#define LD_A(kk, s) (*(const int4*)(Ab + (size_t)(m0 + ((s) >> 2)) * 3072 + (kk) * 64 + ((s) & 3) * 16))
#define LD_B(kk, s) (*(const int4*)(Bb + (size_t)(n0 + ((s) >> 2)) * 3072 + (kk) * 64 + ((s) & 3) * 16))
    ra[0] = LD_A(0, s0); ra[1] = LD_A(0, s1);
    rb[0] = LD_B(0, s0); rb[1] = LD_B(0, s1);
    for (int kk = 0; kk < 48; ++kk) {
        __syncthreads();
        *(int4*)(AsB + d0) = ra[0]; *(int4*)(AsB + d1) = ra[1];
        *(int4*)(BsB + d0) = rb[0]; *(int4*)(BsB + d1) = rb[1];
        __syncthreads();
        if (kk + 1 < 48) {
            ra[0] = LD_A(kk + 1, s0); ra[1] = LD_A(kk + 1, s1);
            rb[0] = LD_B(kk + 1, s0); rb[1] = LD_B(kk + 1, s1);
        }
        f16x8 af[4], bf[4];
#pragma unroll
        for (int i = 0; i < 4; ++i) {
            af[i] = *(const f16x8*)(AsB + (wm + i * 16 + L) * 80 + g * 16);
            bf[i] = *(const f16x8*)(BsB + (wn + i * 16 + L) * 80 + g * 16);
        }
#pragma unroll
        for (int i = 0; i < 4; ++i)
#pragma unroll
            for (int j = 0; j < 4; ++j)
                acc[i][j] = MFMA16(af[i], bf[j], acc[i][j]);
    }
#pragma unroll
    for (int i = 0; i < 4; ++i)
#pragma unroll
        for (int j = 0; j < 4; ++j) {
            int gn = n0 + wn + j * 16 + L;
            float bv = bias[gn];
            int gm = m0 + wm + i * 16 + g * 4;
            float* dst = out + (size_t)gm * 1536 + gn;
#pragma unroll
            for (int r = 0; r < 4; ++r) dst[(size_t)r * 1536] = acc[i][j][r] + bv;
        }
#undef LD_A
#undef LD_B
}

extern "C" void kernel_launch(void* const* d_in, const int* in_sizes, int n_in,
                              void* d_out, int out_size, void* d_ws, size_t ws_size,
                              hipStream_t stream)
{
    const float* x     = (const float*)d_in[0];
    const float* Wqkv  = (const float*)d_in[1];
    const float* Wproj = (const float*)d_in[2];
    const float* bproj = (const float*)d_in[3];
    const float* scale = (const float*)d_in[4];
    const float* M     = (const float*)d_in[5];
    float* out  = (float*)d_out;
    float* attn = out + 6291456;

    char* p = (char*)d_ws;
    f16* x_h     = (f16*)p;  p += 12582912;
    f16* Wqkv_h  = (f16*)p;  p += 14155776;
    f16* Wproj_h = (f16*)p;  p += 4718592;
    f16* Mt_h    = (f16*)p;  p += 73728;
    f16* Qh      = (f16*)p;  p += 12582912;
    f16* Kh      = (f16*)p;  p += 12582912;
    f16* Vp      = (f16*)p;  p += 12582912;
    f16* QMh     = (f16*)p;  p += 12582912;
    float* qmq   = (float*)p; p += 131072;
    float* kmk   = (float*)p; p += 131072;
    float* lrow  = (float*)p; p += 131072;
    f16* ctx     = (f16*)p;  p += 12582912;

    k_cvt<<<6144, 256, 0, stream>>>(x, x_h, 1572864);
    k_cvt<<<6912, 256, 0, stream>>>(Wqkv, Wqkv_h, 1769472);
    k_cvt<<<2304, 256, 0, stream>>>(Wproj, Wproj_h, 589824);
    k_cvtM<<<144, 256, 0, stream>>>(M, Mt_h);
    k_gemm_qkv<<<dim3(36, 32), 256, 0, stream>>>(x_h, Wqkv_h, Qh, Kh, Vp);
    k_mgemm<<<dim3(512, 2), 256, 0, stream>>>(Qh, Kh, Mt_h, QMh, scale, qmq, kmk);
    k_attn<<<512, 256, 0, stream>>>(QMh, Kh, Vp, kmk, qmq, scale, attn, ctx, lrow);
    k_norm<<<4096, 256, 0, stream>>>(attn, lrow);
    k_proj<<<dim3(12, 32), 256, 0, stream>>>(ctx, Wproj_h, bproj, out);
    hipMemcpyAsync(out + 73400320, M, 36864 * 4, hipMemcpyDeviceToDevice, stream);
}

// Round 7
// 447.781 us; speedup vs baseline: 2.2386x; 1.5339x over previous
//
#include <hip/hip_runtime.h>

typedef _Float16 f16;
typedef __attribute__((ext_vector_type(8))) _Float16 f16x8;
typedef __attribute__((ext_vector_type(4))) float f32x4;

#define LOG2E 1.4426950408889634f
#define MFMA16(a, b, c) __builtin_amdgcn_mfma_f32_16x16x32_f16((a), (b), (c), 0, 0, 0)

// B=2, N=2048, C=1536, H=8, D=192.  BH=16, tokens=4096.
// d_out layout: out[2,2048,1536] f32 | attn[2,8,2048,2048] f32 | M[192,192] f32
// MFMA16(X, Y) -> D[lane&15 = Y-row, (lane>>4)*4+r = X-row]

__device__ __forceinline__ void gl16(const void* g, void* l) {
    __builtin_amdgcn_global_load_lds(
        (const __attribute__((address_space(1))) unsigned int*)g,
        (__attribute__((address_space(3))) unsigned int*)l, 16, 0, 0);
}

// ---------------- fp32 -> fp16 converts ----------------
__global__ void k_cvt(const float* __restrict__ src, f16* __restrict__ dst, int n4) {
    int i = blockIdx.x * blockDim.x + threadIdx.x;
    if (i >= n4) return;
    float4 v = ((const float4*)src)[i];
    union { f16 h[4]; short4 s4; } u;
    u.h[0] = (f16)v.x; u.h[1] = (f16)v.y; u.h[2] = (f16)v.z; u.h[3] = (f16)v.w;
    ((short4*)dst)[i] = u.s4;
}

// Mt[d][e] = M[e][d]
__global__ void k_cvtM(const float* __restrict__ M, f16* __restrict__ Mt) {
    int i = blockIdx.x * 256 + threadIdx.x;
    if (i >= 192 * 192) return;
    int d = i / 192, e = i - (i / 192) * 192;
    Mt[d * 192 + e] = (f16)M[e * 192 + d];
}

// ---------------- QKV projection GEMM (async global_load_lds, dbuf, 1 barrier/iter) ----------------
// grid 1152 (XCD-chunked). Q/K blocks: swapped operands -> token-row short4 stores.
// V blocks: unswapped -> Vp[bh][d][2048] permuted-slot short4 stores.
__global__ __launch_bounds__(256) void k_gemm_qkv(
    const f16* __restrict__ A, const f16* __restrict__ Bw,
    f16* __restrict__ Qh, f16* __restrict__ Kh, f16* __restrict__ Vp)
{
    __shared__ __align__(16) char S[32768];   // 2 bufs x (A 8KB + B 8KB)
    const int tid = threadIdx.x, lane = tid & 63, w = tid >> 6;
    const int bid = blockIdx.x;
    const int xcd = bid & 7, cc = bid >> 3;
    const int mb = xcd * 4 + cc / 36, nb = cc - (cc / 36) * 36;
    const int m0 = mb * 128, n0 = nb * 128;
    const int sec = nb >= 24 ? 2 : (nb >= 12 ? 1 : 0);
    const int wm = (w & 1) * 64, wn = (w >> 1) * 64;
    const int L = lane & 15, g = lane >> 4;
    const char* Ab = (const char*)A;
    const char* Bb = (const char*)Bw;

    const char* gA[2]; const char* gB[2]; int ldso[2];
#pragma unroll
    for (int q = 0; q < 2; ++q) {
        int s = w * 128 + q * 64 + lane;
        int swz = ((s & 3) ^ ((s >> 2) & 3)) * 16;    // source pre-swizzle
        gA[q] = Ab + (size_t)(m0 + (s >> 2)) * 3072 + swz;
        gB[q] = Bb + (size_t)(n0 + (s >> 2)) * 3072 + swz;
        ldso[q] = w * 2048 + q * 1024;
    }
    const int gx = ((g ^ (L & 3)) << 4);               // swizzled frag-read slot

    f32x4 acc[4][4] = {};
#pragma unroll
    for (int q = 0; q < 2; ++q) {
        gl16(gA[q], S + ldso[q]);
        gl16(gB[q], S + 8192 + ldso[q]);
    }
    int buf = 0;
    for (int kk = 0; kk < 48; ++kk) {
        __syncthreads();                                // drains vmcnt: tile kk landed
        if (kk < 47) {
            int nb_ = (buf ^ 1) * 16384;
#pragma unroll
            for (int q = 0; q < 2; ++q) {
                gl16(gA[q] + (kk + 1) * 64, S + nb_ + ldso[q]);
                gl16(gB[q] + (kk + 1) * 64, S + nb_ + 8192 + ldso[q]);
            }
        }
        const char* AsB = S + buf * 16384;
        const char* BsB = AsB + 8192;
        f16x8 af[4], bf[4];
#pragma unroll
        for (int i = 0; i < 4; ++i) {
            af[i] = *(const f16x8*)(AsB + (wm + i * 16 + L) * 64 + gx);
            bf[i] = *(const f16x8*)(BsB + (wn + i * 16 + L) * 64 + gx);
        }
        if (sec < 2) {
#pragma unroll
            for (int i = 0; i < 4; ++i)
#pragma unroll
                for (int j = 0; j < 4; ++j)
                    acc[i][j] = MFMA16(bf[j], af[i], acc[i][j]);   // D[L=token, g4r=d]
        } else {
#pragma unroll
            for (int i = 0; i < 4; ++i)
#pragma unroll
                for (int j = 0; j < 4; ++j)
                    acc[i][j] = MFMA16(af[i], bf[j], acc[i][j]);   // D[L=d, g4r=token]
        }
        buf ^= 1;
    }

    if (sec == 2) {
#pragma unroll
        for (int i = 0; i < 4; ++i)
#pragma unroll
            for (int j = 0; j < 4; ++j) {
                int rem = n0 + wn + j * 16 + L - 3072;
                int h = rem / 192, d = rem - h * 192;
                int gm = m0 + wm + i * 16 + g * 4;
                int gb = gm >> 11, nn = gm & 2047;
                union { f16 h4[4]; short4 s4; } u;
#pragma unroll
                for (int r = 0; r < 4; ++r) u.h4[r] = (f16)acc[i][j][r];
                int nnp = (nn & ~31) | (((nn >> 2) & 3) << 3) | (((nn >> 4) & 1) << 2) | (nn & 3);
                *(short4*)(Vp + (size_t)((gb * 8 + h) * 192 + d) * 2048 + nnp) = u.s4;
            }
    } else {
        f16* base = sec == 0 ? Qh : Kh;
#pragma unroll
        for (int i = 0; i < 4; ++i) {
            int gm = m0 + wm + i * 16 + L;          // token
            int gb = gm >> 11, nn = gm & 2047;
#pragma unroll
            for (int j = 0; j < 4; ++j) {
                int rem = n0 + wn + j * 16 + g * 4 - sec * 1536;
                int h = rem / 192, d = rem - h * 192;
                union { f16 h4[4]; short4 s4; } u;
#pragma unroll
                for (int r = 0; r < 4; ++r) u.h4[r] = (f16)acc[i][j][r];
                *(short4*)(base + (size_t)((gb * 8 + h) * 2048 + nn) * 192 + d) = u.s4;
            }
        }
    }
}

// ---------------- apply metric M + row quadratic forms (swapped: token on L) ----------------
__global__ __launch_bounds__(256) void k_mgemm(
    const f16* __restrict__ Qh, const f16* __restrict__ Kh,
    const f16* __restrict__ Mt, f16* __restrict__ QMh,
    const float* __restrict__ scale_p, float* __restrict__ qmq, float* __restrict__ kmk)
{
    const int tid = threadIdx.x, lane = tid & 63, w = tid >> 6;
    const int L = lane & 15, g = lane >> 4;
    const int isK = blockIdx.y;
    const f16* src = isK ? Kh : Qh;
    float* rowdot = isK ? kmk : qmq;
    const int row0 = blockIdx.x * 64 + w * 16;
    const int tokrow = row0 + L;
    f16x8 af[6];
#pragma unroll
    for (int ks = 0; ks < 6; ++ks)
        af[ks] = *(const f16x8*)((const char*)src + (size_t)tokrow * 384 + ks * 64 + g * 16);
    f32x4 acc[12] = {};
#pragma unroll
    for (int ct = 0; ct < 12; ++ct)
#pragma unroll
        for (int ks = 0; ks < 6; ++ks) {
            f16x8 bf = *(const f16x8*)((const char*)Mt + (ct * 16 + L) * 384 + ks * 64 + g * 16);
            acc[ct] = MFMA16(bf, af[ks], acc[ct]);     // D[L=token, g4r = Mt-row (d)]
        }
    if (!isK) {
#pragma unroll
        for (int ct = 0; ct < 12; ++ct) {
            union { f16 h4[4]; short4 s4; } u;
#pragma unroll
            for (int r = 0; r < 4; ++r) u.h4[r] = (f16)acc[ct][r];
            *(short4*)(QMh + (size_t)tokrow * 192 + ct * 16 + g * 4) = u.s4;
        }
    }
    float s = 0.f;
#pragma unroll
    for (int ct = 0; ct < 12; ++ct) {
        union { short4 s4; f16 h[4]; } kv;
        kv.s4 = *(const short4*)(src + (size_t)tokrow * 192 + ct * 16 + g * 4);
#pragma unroll
        for (int r = 0; r < 4; ++r) s += acc[ct][r] * (float)kv.h[r];
    }
    s += __shfl_xor(s, 16); s += __shfl_xor(s, 32);
    if (lane < 16) rowdot[row0 + lane] = s * scale_p[0] * LOG2E;
}

// ---------------- single-pass attention ----------------
__global__ __launch_bounds__(256) void k_attn(
    const f16* __restrict__ QMh, const f16* __restrict__ Kh,
    const f16* __restrict__ Vp, const float* __restrict__ kmk,
    const float* __restrict__ qmq, const float* __restrict__ scale_p,
    float* __restrict__ attn, f16* __restrict__ ctx, float* __restrict__ lrow)
{
    __shared__ __align__(16) char KsB[2][12288];   // K tiles; reused as ctx scratch at end
    __shared__ __align__(16) char VsB[2][15360];
    const int tid = threadIdx.x, lane = tid & 63, w = tid >> 6;
    const int L = lane & 15, g = lane >> 4;
    const int bx = blockIdx.x;
    const int bh = (bx & 7) * 2 + (bx >> 8);
    const int qb = (bx >> 3) & 31;
    const int row0 = qb * 64 + w * 16;
    const float a2 = 2.f * scale_p[0] * LOG2E;

    const char* qbase = (const char*)QMh + (size_t)(bh * 2048 + row0) * 384;
    f16x8 qf[6];
#pragma unroll
    for (int ks = 0; ks < 6; ++ks)
        qf[ks] = *(const f16x8*)(qbase + L * 384 + ks * 64 + g * 16);
    const char* Kb = (const char*)Kh + (size_t)bh * 2048 * 384;
    const char* Vb = (const char*)Vp + (size_t)bh * 192 * 4096;
    const float* kmkrow = kmk + bh * 2048;
    const float Crow = qmq[bh * 2048 + row0 + L];

    int ksrc[3], kdst[3], vsrc[3], vdst[3];
#pragma unroll
    for (int i = 0; i < 3; ++i) {
        int s = tid + 256 * i;
        int r = s / 24, c16 = s - r * 24;
        ksrc[i] = r * 384 + c16 * 16;
        kdst[i] = r * 384 + (((c16 & ~7) | ((c16 & 7) ^ (r & 7))) << 4);
        vsrc[i] = (s >> 2) * 4096 + (s & 3) * 16;
        vdst[i] = (s >> 2) * 80 + (s & 3) * 16;
    }
    int kslot[6];
#pragma unroll
    for (int ks = 0; ks < 6; ++ks) {
        int slot = ks * 4 + g;
        kslot[ks] = (((slot & ~7) | ((slot & 7) ^ (L & 7))) << 4);
    }

    int4 stk[3], stv[3];
#pragma unroll
    for (int i = 0; i < 3; ++i) {
        stk[i] = *(const int4*)(Kb + ksrc[i]);
        stv[i] = *(const int4*)(Vb + vsrc[i]);
    }
    f32x4 cacc[12] = {};
    float lacc = 0.f;
    float m_run = -3.0e38f, sc = 0.f;
    float* arow = attn + (size_t)(bh * 2048 + row0 + L) * 2048;

    for (int c = 0; c < 64; ++c) {
        char* Kl = KsB[c & 1];
        char* Vl = VsB[c & 1];
#pragma unroll
        for (int i = 0; i < 3; ++i) {
            *(int4*)(Kl + kdst[i]) = stk[i];
            *(int4*)(Vl + vdst[i]) = stv[i];
        }
        if (c < 63) {
#pragma unroll
            for (int i = 0; i < 3; ++i) {
                stk[i] = *(const int4*)(Kb + (size_t)(c + 1) * 12288 + ksrc[i]);
                stv[i] = *(const int4*)(Vb + (size_t)(c + 1) * 64 + vsrc[i]);
            }
        }
        __syncthreads();
        f32x4 a0 = {}, a1 = {};
#pragma unroll
        for (int ks = 0; ks < 6; ++ks) {
            f16x8 kf0 = *(const f16x8*)(Kl + L * 384 + kslot[ks]);
            f16x8 kf1 = *(const f16x8*)(Kl + (16 + L) * 384 + kslot[ks]);
            a0 = MFMA16(kf0, qf[ks], a0);
            a1 = MFMA16(kf1, qf[ks], a1);
        }
        float4 km0 = *(const float4*)(kmkrow + c * 32 + g * 4);
        float4 km1 = *(const float4*)(kmkrow + c * 32 + 16 + g * 4);
        float e8[8];
        e8[0] = a2 * a0[0] - km0.x - Crow;
        e8[1] = a2 * a0[1] - km0.y - Crow;
        e8[2] = a2 * a0[2] - km0.z - Crow;
        e8[3] = a2 * a0[3] - km0.w - Crow;
        e8[4] = a2 * a1[0] - km1.x - Crow;
        e8[5] = a2 * a1[1] - km1.y - Crow;
        e8[6] = a2 * a1[2] - km1.z - Crow;
        e8[7] = a2 * a1[3] - km1.w - Crow;
        float mx = fmaxf(fmaxf(fmaxf(e8[0], e8[1]), fmaxf(e8[2], e8[3])),
                         fmaxf(fmaxf(e8[4], e8[5]), fmaxf(e8[6], e8[7])));
        mx = fmaxf(mx, __shfl_xor(mx, 16));
        mx = fmaxf(mx, __shfl_xor(mx, 32));
        if (__any(mx > m_run + 4.f)) {
            float mnew = fmaxf(m_run, mx);
            float fr = __builtin_amdgcn_exp2f(m_run - mnew);
            lacc *= fr;
            float frc[4];
#pragma unroll
            for (int r = 0; r < 4; ++r) frc[r] = __shfl(fr, g * 4 + r);
#pragma unroll
            for (int dt = 0; dt < 12; ++dt)
#pragma unroll
                for (int r = 0; r < 4; ++r) cacc[dt][r] *= frc[r];
            m_run = mnew;
            sc = __builtin_amdgcn_exp2f(-m_run);
        }
        float p[8], ps[8];
#pragma unroll
        for (int j = 0; j < 8; ++j) {
            p[j] = __builtin_amdgcn_exp2f(e8[j]);
            ps[j] = p[j] * sc;
        }
        *(float4*)(arow + c * 32 + g * 4)      = make_float4(p[0], p[1], p[2], p[3]);
        *(float4*)(arow + c * 32 + 16 + g * 4) = make_float4(p[4], p[5], p[6], p[7]);
        lacc += ((ps[0] + ps[1]) + (ps[2] + ps[3])) + ((ps[4] + ps[5]) + (ps[6] + ps[7]));
        f16x8 pa;
        pa[0] = (f16)ps[0]; pa[1] = (f16)ps[1]; pa[2] = (f16)ps[2]; pa[3] = (f16)ps[3];
        pa[4] = (f16)ps[4]; pa[5] = (f16)ps[5]; pa[6] = (f16)ps[6]; pa[7] = (f16)ps[7];
#pragma unroll
        for (int dt = 0; dt < 12; ++dt) {
            f16x8 vf = *(const f16x8*)(Vl + (dt * 16 + L) * 80 + g * 16);
            cacc[dt] = MFMA16(pa, vf, cacc[dt]);
        }
    }
    lacc += __shfl_xor(lacc, 16);
    lacc += __shfl_xor(lacc, 32);
    if (g == 0) lrow[bh * 2048 + row0 + L] = __builtin_amdgcn_exp2f(-m_run) / lacc;
    float linv_r[4];
#pragma unroll
    for (int r = 0; r < 4; ++r) linv_r[r] = 1.f / __shfl(lacc, g * 4 + r);

    // ---- ctx epilogue: per-wave LDS transpose -> full-line stores ----
    __syncthreads();                                   // all waves done with K/V tiles
    char* scr = (char*)KsB + w * 6144;                 // [16 tok][384 B]
#pragma unroll
    for (int dt = 0; dt < 12; ++dt)
#pragma unroll
        for (int r = 0; r < 4; ++r)
            *(f16*)(scr + (g * 4 + r) * 384 + (dt * 16 + L) * 2)
                = (f16)(cacc[dt][r] * linv_r[r]);
    const int b = bh >> 3, h = bh & 7;
#pragma unroll
    for (int t = 0; t < 6; ++t) {
        int chunk = t * 64 + lane;
        int tok = chunk / 24, c16 = chunk - tok * 24;
        int4 v = *(const int4*)(scr + tok * 384 + c16 * 16);
        *(int4*)((char*)ctx + ((size_t)(b * 2048 + row0 + tok) * 1536 + h * 192) * 2 + c16 * 16) = v;
    }
}

// ---------------- streaming in-place normalize of attn (32768 rows) ----------------
__global__ __launch_bounds__(256) void k_norm(float* __restrict__ attn,
                                              const float* __restrict__ lrow)
{
    const int row = blockIdx.x * 8 + (threadIdx.x >> 5);
    const int t = threadIdx.x & 31;
    const float f = lrow[row];
    float4* p = (float4*)(attn + (size_t)row * 2048) + t;
#pragma unroll
    for (int i = 0; i < 16; ++i) {
        float4 v = p[(size_t)i * 32];
        v.x *= f; v.y *= f; v.z *= f; v.w *= f;
        p[(size_t)i * 32] = v;
    }
}

// ---------------- output projection GEMM + bias (async, swapped, float4 stores) ----------------
__global__ __launch_bounds__(256) void k_proj(
    const f16* __restrict__ A, const f16* __restrict__ Bw,
    const float* __restrict__ bias, float* __restrict__ out)
{
    __shared__ __align__(16) char S[32768];
    const int tid = threadIdx.x, lane = tid & 63, w = tid >> 6;
    const int bid = blockIdx.x;
    const int xcd = bid & 7, cc = bid >> 3;
    const int mb = xcd * 4 + cc / 12, nbk = cc - (cc / 12) * 12;
    const int m0 = mb * 128, n0 = nbk * 128;
    const int wm = (w & 1) * 64, wn = (w >> 1) * 64;
    const int L = lane & 15, g = lane >> 4;
    const char* Ab = (const char*)A;
    const char* Bb = (const char*)Bw;

    const char* gA[2]; const char* gB[2]; int ldso[2];
#pragma unroll
    for (int q = 0; q < 2; ++q) {
        int s = w * 128 + q * 64 + lane;
        int swz = ((s & 3) ^ ((s >> 2) & 3)) * 16;
        gA[q] = Ab + (size_t)(m0 + (s >> 2)) * 3072 + swz;
        gB[q] = Bb + (size_t)(n0 + (s >> 2)) * 3072 + swz;
        ldso[q] = w * 2048 + q * 1024;
    }
    const int gx = ((g ^ (L & 3)) << 4);

    f32x4 acc[4][4] = {};
#pragma unroll
    for (int q = 0; q < 2; ++q) {
        gl16(gA[q], S + ldso[q]);
        gl16(gB[q], S + 8192 + ldso[q]);
    }
    int buf = 0;
    for (int kk = 0; kk < 48; ++kk) {
        __syncthreads();
        if (kk < 47) {
            int nb_ = (buf ^ 1) * 16384;
#pragma unroll
            for (int q = 0; q < 2; ++q) {
                gl16(gA[q] + (kk + 1) * 64, S + nb_ + ldso[q]);
                gl16(gB[q] + (kk + 1) * 64, S + nb_ + 8192 + ldso[q]);
            }
        }
        const char* AsB = S + buf * 16384;
        const char* BsB = AsB + 8192;
        f16x8 af[4], bf[4];
#pragma unroll
        for (int i = 0; i < 4; ++i) {
            af[i] = *(const f16x8*)(AsB + (wm + i * 16 + L) * 64 + gx);
            bf[i] = *(const f16x8*)(BsB + (wn + i * 16 + L) * 64 + gx);
        }
#pragma unroll
        for (int i = 0; i < 4; ++i)
#pragma unroll
            for (int j = 0; j < 4; ++j)
                acc[i][j] = MFMA16(bf[j], af[i], acc[i][j]);   // D[L=token, g4r=col]
        buf ^= 1;
    }
#pragma unroll
    for (int i = 0; i < 4; ++i) {
        int token = m0 + wm + i * 16 + L;
#pragma unroll
        for (int j = 0; j < 4; ++j) {
            int gnb = n0 + wn + j * 16 + g * 4;
            float4 bv = *(const float4*)(bias + gnb);
            float4 v = make_float4(acc[i][j][0] + bv.x, acc[i][j][1] + bv.y,
                                   acc[i][j][2] + bv.z, acc[i][j][3] + bv.w);
            *(float4*)(out + (size_t)token * 1536 + gnb) = v;
        }
    }
}

extern "C" void kernel_launch(void* const* d_in, const int* in_sizes, int n_in,
                              void* d_out, int out_size, void* d_ws, size_t ws_size,
                              hipStream_t stream)
{
    const float* x     = (const float*)d_in[0];
    const float* Wqkv  = (const float*)d_in[1];
    const float* Wproj = (const float*)d_in[2];
    const float* bproj = (const float*)d_in[3];
    const float* scale = (const float*)d_in[4];
    const float* M     = (const float*)d_in[5];
    float* out  = (float*)d_out;
    float* attn = out + 6291456;

    char* p = (char*)d_ws;
    f16* x_h     = (f16*)p;  p += 12582912;
    f16* Wqkv_h  = (f16*)p;  p += 14155776;
    f16* Wproj_h = (f16*)p;  p += 4718592;
    f16* Mt_h    = (f16*)p;  p += 73728;
    f16* Qh      = (f16*)p;  p += 12582912;
    f16* Kh      = (f16*)p;  p += 12582912;
    f16* Vp      = (f16*)p;  p += 12582912;
    f16* QMh     = (f16*)p;  p += 12582912;
    float* qmq   = (float*)p; p += 131072;
    float* kmk   = (float*)p; p += 131072;
    float* lrow  = (float*)p; p += 131072;
    f16* ctx     = (f16*)p;  p += 12582912;

    k_cvt<<<6144, 256, 0, stream>>>(x, x_h, 1572864);
    k_cvt<<<6912, 256, 0, stream>>>(Wqkv, Wqkv_h, 1769472);
    k_cvt<<<2304, 256, 0, stream>>>(Wproj, Wproj_h, 589824);
    k_cvtM<<<144, 256, 0, stream>>>(M, Mt_h);
    k_gemm_qkv<<<1152, 256, 0, stream>>>(x_h, Wqkv_h, Qh, Kh, Vp);
    k_mgemm<<<dim3(512, 2), 256, 0, stream>>>(Qh, Kh, Mt_h, QMh, scale, qmq, kmk);
    k_attn<<<512, 256, 0, stream>>>(QMh, Kh, Vp, kmk, qmq, scale, attn, ctx, lrow);
    k_norm<<<4096, 256, 0, stream>>>(attn, lrow);
    k_proj<<<384, 256, 0, stream>>>(ctx, Wproj_h, bproj, out);
    hipMemcpyAsync(out + 73400320, M, 36864 * 4, hipMemcpyDeviceToDevice, stream);
}